// Round 1
// baseline (145.667 us; speedup 1.0000x reference)
//
#include <hip/hip_runtime.h>

#define DIN 256
#define DHID 256
#define DEDGE 64
#define GS 68       // fp32 LDS tile row stride (dwords): 272 B, 16B-aligned, conflict-free

typedef float f32x4 __attribute__((ext_vector_type(4)));
typedef short s16x8 __attribute__((ext_vector_type(8)));
typedef unsigned int u32x4 __attribute__((ext_vector_type(4)));

// HW RNE pack: dst = {bf16(lo), bf16(hi)} — replaces ~10 ALU ops of manual RNE.
__device__ __forceinline__ unsigned int cvtpk(float lo, float hi) {
    unsigned int r;
    asm("v_cvt_pk_bf16_f32 %0, %1, %2" : "=v"(r) : "v"(lo), "v"(hi));
    return r;
}

// -------- Kernel W: weight pre-fusion.
// CW[n][d] = sum_h W1row(n)[h] * Win[h][d], n<256 -> Wa half, n>=256 -> Wb half.
// K-split 2 over h (kc stride 1<<17). Block 64 computes c[g] = (Wa+Wb)rowg . b_in + b1[g].
__global__ __launch_bounds__(256) void k_w(
    const float* __restrict__ Win, const float* __restrict__ W1,
    const float* __restrict__ bin, const float* __restrict__ b1,
    float* __restrict__ CWp, float* __restrict__ cb)
{
    const int bid = blockIdx.x;
    const int tid = threadIdx.x;
    if (bid == 64) {
        float acc = b1[tid];
        const float* wrow = &W1[tid * 512];
        for (int h = 0; h < 256; h += 4) {
            const f32x4 wa = *reinterpret_cast<const f32x4*>(&wrow[h]);
            const f32x4 wb = *reinterpret_cast<const f32x4*>(&wrow[256 + h]);
            const f32x4 bv = *reinterpret_cast<const f32x4*>(&bin[h]);
            acc += (wa[0]+wb[0])*bv[0] + (wa[1]+wb[1])*bv[1]
                 + (wa[2]+wb[2])*bv[2] + (wa[3]+wb[3])*bv[3];
        }
        cb[tid] = acc;
        return;
    }
    __shared__ float as[64 * GS];
    __shared__ float ws2[64 * GS];
    const int kc = bid >> 5;
    const int nt = (bid >> 2) & 7;
    const int dt = bid & 3;
    const int n0 = nt << 6, d0 = dt << 6;
    const int na = n0 & 255;          // W1 row base
    const int hb = (n0 >> 8) << 8;    // Wa/Wb column half
    const int rr = tid >> 4, kk = (tid & 15) << 2;
    const int tx = tid & 15, ty = tid >> 4;

    float acc[4][4] = {};
    for (int kt = 0; kt < 2; ++kt) {
        const int h0 = (kc << 7) + (kt << 6);
        if (kt) __syncthreads();
#pragma unroll
        for (int it = 0; it < 4; ++it) {
            const int row = rr + (it << 4);
            *reinterpret_cast<f32x4*>(&as[row * GS + kk]) =
                *reinterpret_cast<const f32x4*>(&W1[(na + row) * 512 + hb + h0 + kk]);
            *reinterpret_cast<f32x4*>(&ws2[row * GS + kk]) =
                *reinterpret_cast<const f32x4*>(&Win[(h0 + row) * DIN + d0 + kk]);
        }
        __syncthreads();
        // as is K-contiguous; ws2 is [k][d] (K-major) -> column reads, broadcast-friendly.
        for (int k = 0; k < 64; k += 4) {
            f32x4 av[4];
#pragma unroll
            for (int r = 0; r < 4; ++r)
                av[r] = *reinterpret_cast<const f32x4*>(&as[(ty + (r << 4)) * GS + k]);
#pragma unroll
            for (int k2 = 0; k2 < 4; ++k2) {
                float bcol[4];
#pragma unroll
                for (int c = 0; c < 4; ++c)
                    bcol[c] = ws2[(k + k2) * GS + tx + (c << 4)];
#pragma unroll
                for (int r = 0; r < 4; ++r)
#pragma unroll
                    for (int c = 0; c < 4; ++c)
                        acc[r][c] += av[r][k2] * bcol[c];
            }
        }
    }
    float* dst = CWp + ((size_t)kc << 17);
#pragma unroll
    for (int r = 0; r < 4; ++r)
#pragma unroll
        for (int c = 0; c < 4; ++c)
            dst[(n0 + ty + (r << 4)) * 256 + d0 + tx + (c << 4)] = acc[r][c];
}

// -------- Kernel P: pap/pbp[kc][m][g] = sum_{d in 128-chunk kc} x[m][d]*CW[half*256+g][d]
// CW = CWp0 + CWp1 summed in staging. grid (16 mt, 8 = 4nt*2half, 2 kc) = 256 blocks.
__global__ __launch_bounds__(256) void k_pab(
    const float* __restrict__ x, const float* __restrict__ CWp,
    float* __restrict__ pap, float* __restrict__ pbp)
{
    __shared__ float as[64 * GS];
    __shared__ float ws2[64 * GS];
    const int m0 = blockIdx.x << 6;
    const int half = blockIdx.y >> 2;
    const int n0 = (blockIdx.y & 3) << 6;
    const int kc = blockIdx.z;
    const int tid = threadIdx.x;
    const int rr = tid >> 4, kk = (tid & 15) << 2;
    const int tx = tid & 15, ty = tid >> 4;

    float acc[4][4] = {};
    for (int kt = 0; kt < 2; ++kt) {
        const int k0 = (kc << 7) + (kt << 6);
        if (kt) __syncthreads();
#pragma unroll
        for (int it = 0; it < 4; ++it) {
            const int row = rr + (it << 4);
            *reinterpret_cast<f32x4*>(&as[row * GS + kk]) =
                *reinterpret_cast<const f32x4*>(&x[(m0 + row) * DIN + k0 + kk]);
            const float* wr = &CWp[((half << 8) + n0 + row) * 256 + k0 + kk];
            const f32x4 wv = *reinterpret_cast<const f32x4*>(wr)
                           + *reinterpret_cast<const f32x4*>(wr + (1 << 17));
            *reinterpret_cast<f32x4*>(&ws2[row * GS + kk]) = wv;
        }
        __syncthreads();

        for (int k = 0; k < 64; k += 4) {
            f32x4 av[4], wv[4];
#pragma unroll
            for (int r = 0; r < 4; ++r)
                av[r] = *reinterpret_cast<const f32x4*>(&as[(ty + (r << 4)) * GS + k]);
#pragma unroll
            for (int c = 0; c < 4; ++c)
                wv[c] = *reinterpret_cast<const f32x4*>(&ws2[(tx + (c << 4)) * GS + k]);
#pragma unroll
            for (int r = 0; r < 4; ++r)
#pragma unroll
                for (int c = 0; c < 4; ++c)
                    acc[r][c] += av[r][0]*wv[c][0] + av[r][1]*wv[c][1]
                               + av[r][2]*wv[c][2] + av[r][3]*wv[c][3];
        }
    }
    float* dst = (half ? pbp : pap) + ((size_t)kc << 18);
#pragma unroll
    for (int r = 0; r < 4; ++r)
#pragma unroll
        for (int c = 0; c < 4; ++c)
            dst[(m0 + ty + (r << 4)) * DHID + n0 + tx + (c << 4)] = acc[r][c];
}

// -------- Kernel 3: fused z=silu(pa_i+pb_j+c); out = z@W2^T + b2 (MFMA) ----
// grid (4 jb, 64 i/4, 4 b), 256 thr = 4 waves; wave: 16 j x 64 e, 4 i at once.
// W2 staged in LDS pre-swizzled into MFMA B-fragment order:
//   frag f=(k0*4+eb)*64+lane = W2bf16[eb*16+l15][k0*32+quad*8 .. +8]
// -> bfrag ds_read_b128 is lane-linear = bank-conflict-free (old pad layout was 8-way).
__global__ __launch_bounds__(256) void k_out(
    const float* __restrict__ pap, const float* __restrict__ pbp,
    const float* __restrict__ cb, const float* __restrict__ W2,
    const float* __restrict__ b2, float* __restrict__ out)
{
    __shared__ s16x8 w2s[2048];      // 32 KB, fragment layout
    __shared__ float pab1[4][DHID];  // 4 KB

    const int jb = blockIdx.x, i0 = blockIdx.y << 2, b = blockIdx.z;
    const int tid = threadIdx.x;

    {
        const float cv = cb[tid];
#pragma unroll
        for (int ii = 0; ii < 4; ++ii) {
            const int off = (((b << 8) + i0 + ii) << 8) + tid;
            pab1[ii][tid] = pap[off] + pap[off + (1 << 18)] + cv;
        }
    }
#pragma unroll
    for (int it = 0; it < 8; ++it) {
        const int f = tid + (it << 8);
        const int l15f = f & 15, qf = (f >> 4) & 3, ebf = (f >> 6) & 3, k0f = f >> 8;
        const int row = (ebf << 4) + l15f;
        const int col = (k0f << 5) + (qf << 3);
        const f32x4 w0 = *reinterpret_cast<const f32x4*>(&W2[row * DHID + col]);
        const f32x4 w1 = *reinterpret_cast<const f32x4*>(&W2[row * DHID + col + 4]);
        u32x4 wp;
        wp[0] = cvtpk(w0[0], w0[1]); wp[1] = cvtpk(w0[2], w0[3]);
        wp[2] = cvtpk(w1[0], w1[1]); wp[3] = cvtpk(w1[2], w1[3]);
        w2s[f] = __builtin_bit_cast(s16x8, wp);
    }
    __syncthreads();

    const int lane = tid & 63, wave = tid >> 6, quad = lane >> 4, l15 = lane & 15;
    const int j0 = (jb << 6) + (wave << 4);
    const int pboff = (((b << 8) + (j0 + l15)) << 8);
    const float* pbq0 = pbp + pboff;
    const float* pbq1 = pbp + (1 << 18) + pboff;

    f32x4 acc[4][4];   // [ii][eb]
#pragma unroll
    for (int ii = 0; ii < 4; ++ii)
#pragma unroll
        for (int eb = 0; eb < 4; ++eb) acc[ii][eb] = (f32x4){0.f, 0.f, 0.f, 0.f};

    float b2v[4];
#pragma unroll
    for (int eb = 0; eb < 4; ++eb) b2v[eb] = b2[(eb << 4) + l15];

    for (int k0 = 0; k0 < 8; ++k0) {
        const int g = (k0 << 5) + (quad << 3);
        const f32x4 p0 = *reinterpret_cast<const f32x4*>(pbq0 + g)
                       + *reinterpret_cast<const f32x4*>(pbq1 + g);
        const f32x4 p1 = *reinterpret_cast<const f32x4*>(pbq0 + g + 4)
                       + *reinterpret_cast<const f32x4*>(pbq1 + g + 4);

        s16x8 bfrag[4];
#pragma unroll
        for (int eb = 0; eb < 4; ++eb)
            bfrag[eb] = w2s[((k0 << 2) + eb) * 64 + lane];

#pragma unroll
        for (int ii = 0; ii < 4; ++ii) {
            const f32x4 q0 = *reinterpret_cast<const f32x4*>(&pab1[ii][g]);
            const f32x4 q1 = *reinterpret_cast<const f32x4*>(&pab1[ii][g + 4]);
            float s[8];
#pragma unroll
            for (int jj = 0; jj < 4; ++jj) {
                const float z0 = q0[jj] + p0[jj];
                const float z1 = q1[jj] + p1[jj];
                const float e0 = __expf(-z0);
                const float e1 = __expf(-z1);
                s[jj]     = z0 * __builtin_amdgcn_rcpf(1.0f + e0);
                s[4 + jj] = z1 * __builtin_amdgcn_rcpf(1.0f + e1);
            }
            u32x4 ap;
            ap[0] = cvtpk(s[0], s[1]); ap[1] = cvtpk(s[2], s[3]);
            ap[2] = cvtpk(s[4], s[5]); ap[3] = cvtpk(s[6], s[7]);
            const s16x8 a = __builtin_bit_cast(s16x8, ap);
#pragma unroll
            for (int eb = 0; eb < 4; ++eb)
                acc[ii][eb] = __builtin_amdgcn_mfma_f32_16x16x32_bf16(a, bfrag[eb], acc[ii][eb], 0, 0, 0);
        }
    }

#pragma unroll
    for (int ii = 0; ii < 4; ++ii) {
        const int obase = (((((b << 8) + i0 + ii) << 8) + j0 + (quad << 2)) << 6) + l15;
#pragma unroll
        for (int eb = 0; eb < 4; ++eb) {
#pragma unroll
            for (int r = 0; r < 4; ++r)
                __builtin_nontemporal_store(acc[ii][eb][r] + b2v[eb],
                                            &out[obase + (r << 6) + (eb << 4)]);
        }
    }
}

extern "C" void kernel_launch(void* const* d_in, const int* in_sizes, int n_in,
                              void* d_out, int out_size, void* d_ws, size_t ws_size,
                              hipStream_t stream) {
    const float* x = 0; const float* Win = 0; const float* bin = 0;
    const float* W1 = 0; const float* b1 = 0; const float* W2 = 0; const float* b2 = 0;
    for (int idx = 0; idx < n_in; ++idx) {
        const int s = in_sizes[idx];
        if (s == 262144) x = (const float*)d_in[idx];
        else if (s == 131072) W1 = (const float*)d_in[idx];
        else if (s == 65536) Win = (const float*)d_in[idx];
        else if (s == 16384) W2 = (const float*)d_in[idx];
        else if (s == 64) b2 = (const float*)d_in[idx];
        else if (s == 256) { if (!bin) bin = (const float*)d_in[idx]; else b1 = (const float*)d_in[idx]; }
    }

    // workspace: CWp 2x131072 | cb 256 | pap 2x262144 | pbp 2x262144  (~5.3 MB of 256 MiB)
    float* ws = (float*)d_ws;
    float* CWp = ws;
    float* cb  = ws + (1 << 18);
    float* pap = ws + (1 << 18) + 256;
    float* pbp = pap + (1 << 19);

    hipLaunchKernelGGL(k_w,   dim3(65),       dim3(256), 0, stream, Win, W1, bin, b1, CWp, cb);
    hipLaunchKernelGGL(k_pab, dim3(16, 8, 2), dim3(256), 0, stream, x, CWp, pap, pbp);
    hipLaunchKernelGGL(k_out, dim3(4, 64, 4), dim3(256), 0, stream, pap, pbp, cb, W2, b2, (float*)d_out);
}

// Round 2
// 137.448 us; speedup vs baseline: 1.0598x; 1.0598x over previous
//
#include <hip/hip_runtime.h>

#define DIN 256
#define DHID 256
#define DEDGE 64
#define GS 68       // fp32 LDS tile row stride (dwords): 272 B, 16B-aligned, conflict-free

typedef float f32x4 __attribute__((ext_vector_type(4)));
typedef short s16x8 __attribute__((ext_vector_type(8)));
typedef unsigned int u32x4 __attribute__((ext_vector_type(4)));

// HW RNE pack: dst = {bf16(lo), bf16(hi)}
__device__ __forceinline__ unsigned int cvtpk(float lo, float hi) {
    unsigned int r;
    asm("v_cvt_pk_bf16_f32 %0, %1, %2" : "=v"(r) : "v"(lo), "v"(hi));
    return r;
}

// -------- Kernel W: weight pre-fusion + W2 fragment-order precompute.
// blocks 0..127: CW[n][d] = sum_h W1row(n)[h] * Win[h][d], K-split 4 over h.
// block 128:     cb[g] = (Wa+Wb)rowg . b_in + b1[g]
// block 129:     W2f[f] = W2 in bf16 MFMA-B-fragment order (one-time scatter, 64 KB)
__global__ __launch_bounds__(256) void k_w(
    const float* __restrict__ Win, const float* __restrict__ W1,
    const float* __restrict__ bin, const float* __restrict__ b1,
    const float* __restrict__ W2,
    float* __restrict__ CWp, float* __restrict__ cb, s16x8* __restrict__ W2f)
{
    const int bid = blockIdx.x;
    const int tid = threadIdx.x;
    if (bid >= 128) {
        if (bid == 128) {
            float acc = b1[tid];
            const float* wrow = &W1[tid * 512];
            for (int h = 0; h < 256; h += 4) {
                const f32x4 wa = *reinterpret_cast<const f32x4*>(&wrow[h]);
                const f32x4 wb = *reinterpret_cast<const f32x4*>(&wrow[256 + h]);
                const f32x4 bv = *reinterpret_cast<const f32x4*>(&bin[h]);
                acc += (wa[0]+wb[0])*bv[0] + (wa[1]+wb[1])*bv[1]
                     + (wa[2]+wb[2])*bv[2] + (wa[3]+wb[3])*bv[3];
            }
            cb[tid] = acc;
        } else {
            // fragment f=(k0*4+eb)*64 + quad*16 + l15  <-  W2[eb*16+l15][k0*32+quad*8 ..+8]
#pragma unroll
            for (int j = 0; j < 8; ++j) {
                const int f = tid + (j << 8);
                const int l15f = f & 15, qf = (f >> 4) & 3, ebf = (f >> 6) & 3, k0f = f >> 8;
                const int row = (ebf << 4) + l15f;
                const int col = (k0f << 5) + (qf << 3);
                const f32x4 w0 = *reinterpret_cast<const f32x4*>(&W2[row * DHID + col]);
                const f32x4 w1 = *reinterpret_cast<const f32x4*>(&W2[row * DHID + col + 4]);
                u32x4 wp;
                wp[0] = cvtpk(w0[0], w0[1]); wp[1] = cvtpk(w0[2], w0[3]);
                wp[2] = cvtpk(w1[0], w1[1]); wp[3] = cvtpk(w1[2], w1[3]);
                W2f[f] = __builtin_bit_cast(s16x8, wp);
            }
        }
        return;
    }

    __shared__ float as[64 * GS];
    __shared__ float ws2[64 * GS];
    const int kc = bid >> 5;          // 0..3, 64-wide h-chunk
    const int nt = (bid >> 2) & 7;
    const int dt = bid & 3;
    const int n0 = nt << 6, d0 = dt << 6, h0 = kc << 6;
    const int na = n0 & 255;          // W1 row base
    const int hb = (n0 >> 8) << 8;    // Wa/Wb column half
    const int rr = tid >> 4, kk = (tid & 15) << 2;
    const int tx = tid & 15, ty = tid >> 4;

#pragma unroll
    for (int it = 0; it < 4; ++it) {
        const int row = rr + (it << 4);
        *reinterpret_cast<f32x4*>(&as[row * GS + kk]) =
            *reinterpret_cast<const f32x4*>(&W1[(na + row) * 512 + hb + h0 + kk]);
        *reinterpret_cast<f32x4*>(&ws2[row * GS + kk]) =
            *reinterpret_cast<const f32x4*>(&Win[(h0 + row) * DIN + d0 + kk]);
    }
    __syncthreads();

    float acc[4][4] = {};
    // as is K-contiguous; ws2 is [k][d] (K-major) -> column reads, broadcast-friendly.
    for (int k = 0; k < 64; k += 4) {
        f32x4 av[4];
#pragma unroll
        for (int r = 0; r < 4; ++r)
            av[r] = *reinterpret_cast<const f32x4*>(&as[(ty + (r << 4)) * GS + k]);
#pragma unroll
        for (int k2 = 0; k2 < 4; ++k2) {
            float bcol[4];
#pragma unroll
            for (int c = 0; c < 4; ++c)
                bcol[c] = ws2[(k + k2) * GS + tx + (c << 4)];
#pragma unroll
            for (int r = 0; r < 4; ++r)
#pragma unroll
                for (int c = 0; c < 4; ++c)
                    acc[r][c] += av[r][k2] * bcol[c];
        }
    }
    float* dst = CWp + ((size_t)kc << 17);
#pragma unroll
    for (int r = 0; r < 4; ++r)
#pragma unroll
        for (int c = 0; c < 4; ++c)
            dst[(n0 + ty + (r << 4)) * 256 + d0 + tx + (c << 4)] = acc[r][c];
}

// -------- Kernel P: pap/pbp[kc][m][g] = sum_{d in 128-chunk kc} x[m][d]*CW[half*256+g][d]
// CW = sum of 4 K-split partials, folded into staging. grid (16 mt, 8 = 4nt*2half, 2 kc).
__global__ __launch_bounds__(256) void k_pab(
    const float* __restrict__ x, const float* __restrict__ CWp,
    float* __restrict__ pap, float* __restrict__ pbp)
{
    __shared__ float as[64 * GS];
    __shared__ float ws2[64 * GS];
    const int m0 = blockIdx.x << 6;
    const int half = blockIdx.y >> 2;
    const int n0 = (blockIdx.y & 3) << 6;
    const int kc = blockIdx.z;
    const int tid = threadIdx.x;
    const int rr = tid >> 4, kk = (tid & 15) << 2;
    const int tx = tid & 15, ty = tid >> 4;

    float acc[4][4] = {};
    for (int kt = 0; kt < 2; ++kt) {
        const int k0 = (kc << 7) + (kt << 6);
        if (kt) __syncthreads();
#pragma unroll
        for (int it = 0; it < 4; ++it) {
            const int row = rr + (it << 4);
            *reinterpret_cast<f32x4*>(&as[row * GS + kk]) =
                *reinterpret_cast<const f32x4*>(&x[(m0 + row) * DIN + k0 + kk]);
            const float* wr = &CWp[((half << 8) + n0 + row) * 256 + k0 + kk];
            const f32x4 wv = *reinterpret_cast<const f32x4*>(wr)
                           + *reinterpret_cast<const f32x4*>(wr + (1 << 17))
                           + *reinterpret_cast<const f32x4*>(wr + (2 << 17))
                           + *reinterpret_cast<const f32x4*>(wr + (3 << 17));
            *reinterpret_cast<f32x4*>(&ws2[row * GS + kk]) = wv;
        }
        __syncthreads();

        for (int k = 0; k < 64; k += 4) {
            f32x4 av[4], wv[4];
#pragma unroll
            for (int r = 0; r < 4; ++r)
                av[r] = *reinterpret_cast<const f32x4*>(&as[(ty + (r << 4)) * GS + k]);
#pragma unroll
            for (int c = 0; c < 4; ++c)
                wv[c] = *reinterpret_cast<const f32x4*>(&ws2[(tx + (c << 4)) * GS + k]);
#pragma unroll
            for (int r = 0; r < 4; ++r)
#pragma unroll
                for (int c = 0; c < 4; ++c)
                    acc[r][c] += av[r][0]*wv[c][0] + av[r][1]*wv[c][1]
                               + av[r][2]*wv[c][2] + av[r][3]*wv[c][3];
        }
    }
    float* dst = (half ? pbp : pap) + ((size_t)kc << 18);
#pragma unroll
    for (int r = 0; r < 4; ++r)
#pragma unroll
        for (int c = 0; c < 4; ++c)
            dst[(m0 + ty + (r << 4)) * DHID + n0 + tx + (c << 4)] = acc[r][c];
}

// -------- Kernel 3: fused z=silu(pa_i+pb_j+c); out = z@W2^T + b2 (MFMA) ----
// grid (4 jb, 64 i/4, 4 b), 256 thr = 4 waves; wave: 16 j x 64 e, 4 i at once.
// W2 arrives pre-converted in fragment order (W2f) -> staging is a linear s16x8
// copy: coalesced global reads AND conflict-free linear LDS writes.
__global__ __launch_bounds__(256) void k_out(
    const float* __restrict__ pap, const float* __restrict__ pbp,
    const float* __restrict__ cb, const s16x8* __restrict__ W2f,
    const float* __restrict__ b2, float* __restrict__ out)
{
    __shared__ s16x8 w2s[2048];      // 32 KB, fragment layout
    __shared__ float pab1[4][DHID];  // 4 KB

    const int jb = blockIdx.x, i0 = blockIdx.y << 2, b = blockIdx.z;
    const int tid = threadIdx.x;

    {
        const float cv = cb[tid];
#pragma unroll
        for (int ii = 0; ii < 4; ++ii) {
            const int off = (((b << 8) + i0 + ii) << 8) + tid;
            pab1[ii][tid] = pap[off] + pap[off + (1 << 18)] + cv;
        }
    }
#pragma unroll
    for (int it = 0; it < 8; ++it)
        w2s[tid + (it << 8)] = W2f[tid + (it << 8)];
    __syncthreads();

    const int lane = tid & 63, wave = tid >> 6, quad = lane >> 4, l15 = lane & 15;
    const int j0 = (jb << 6) + (wave << 4);
    const int pboff = (((b << 8) + (j0 + l15)) << 8);
    const float* pbq0 = pbp + pboff;
    const float* pbq1 = pbp + (1 << 18) + pboff;

    f32x4 acc[4][4];   // [ii][eb]
#pragma unroll
    for (int ii = 0; ii < 4; ++ii)
#pragma unroll
        for (int eb = 0; eb < 4; ++eb) acc[ii][eb] = (f32x4){0.f, 0.f, 0.f, 0.f};

    float b2v[4];
#pragma unroll
    for (int eb = 0; eb < 4; ++eb) b2v[eb] = b2[(eb << 4) + l15];

    for (int k0 = 0; k0 < 8; ++k0) {
        const int g = (k0 << 5) + (quad << 3);
        const f32x4 p0 = *reinterpret_cast<const f32x4*>(pbq0 + g)
                       + *reinterpret_cast<const f32x4*>(pbq1 + g);
        const f32x4 p1 = *reinterpret_cast<const f32x4*>(pbq0 + g + 4)
                       + *reinterpret_cast<const f32x4*>(pbq1 + g + 4);

        s16x8 bfrag[4];
#pragma unroll
        for (int eb = 0; eb < 4; ++eb)
            bfrag[eb] = w2s[((k0 << 2) + eb) * 64 + lane];

#pragma unroll
        for (int ii = 0; ii < 4; ++ii) {
            const f32x4 q0 = *reinterpret_cast<const f32x4*>(&pab1[ii][g]);
            const f32x4 q1 = *reinterpret_cast<const f32x4*>(&pab1[ii][g + 4]);
            float s[8];
#pragma unroll
            for (int jj = 0; jj < 4; ++jj) {
                const float z0 = q0[jj] + p0[jj];
                const float z1 = q1[jj] + p1[jj];
                const float e0 = __expf(-z0);
                const float e1 = __expf(-z1);
                s[jj]     = z0 * __builtin_amdgcn_rcpf(1.0f + e0);
                s[4 + jj] = z1 * __builtin_amdgcn_rcpf(1.0f + e1);
            }
            u32x4 ap;
            ap[0] = cvtpk(s[0], s[1]); ap[1] = cvtpk(s[2], s[3]);
            ap[2] = cvtpk(s[4], s[5]); ap[3] = cvtpk(s[6], s[7]);
            const s16x8 a = __builtin_bit_cast(s16x8, ap);
#pragma unroll
            for (int eb = 0; eb < 4; ++eb)
                acc[ii][eb] = __builtin_amdgcn_mfma_f32_16x16x32_bf16(a, bfrag[eb], acc[ii][eb], 0, 0, 0);
        }
    }

#pragma unroll
    for (int ii = 0; ii < 4; ++ii) {
        const int obase = (((((b << 8) + i0 + ii) << 8) + j0 + (quad << 2)) << 6) + l15;
#pragma unroll
        for (int eb = 0; eb < 4; ++eb) {
#pragma unroll
            for (int r = 0; r < 4; ++r)
                __builtin_nontemporal_store(acc[ii][eb][r] + b2v[eb],
                                            &out[obase + (r << 6) + (eb << 4)]);
        }
    }
}

extern "C" void kernel_launch(void* const* d_in, const int* in_sizes, int n_in,
                              void* d_out, int out_size, void* d_ws, size_t ws_size,
                              hipStream_t stream) {
    const float* x = 0; const float* Win = 0; const float* bin = 0;
    const float* W1 = 0; const float* b1 = 0; const float* W2 = 0; const float* b2 = 0;
    for (int idx = 0; idx < n_in; ++idx) {
        const int s = in_sizes[idx];
        if (s == 262144) x = (const float*)d_in[idx];
        else if (s == 131072) W1 = (const float*)d_in[idx];
        else if (s == 65536) Win = (const float*)d_in[idx];
        else if (s == 16384) W2 = (const float*)d_in[idx];
        else if (s == 64) b2 = (const float*)d_in[idx];
        else if (s == 256) { if (!bin) bin = (const float*)d_in[idx]; else b1 = (const float*)d_in[idx]; }
    }

    // ws layout (floats): CWp 4x(1<<17) | cb 256 | W2f 8192 | pap 2x(1<<18) | pbp 2x(1<<18)
    float* ws  = (float*)d_ws;
    float* CWp = ws;
    float* cb  = ws + (1 << 19);
    float* w2f = cb + 256;
    float* pap = w2f + 8192;
    float* pbp = pap + (1 << 19);

    hipLaunchKernelGGL(k_w,   dim3(130),      dim3(256), 0, stream,
                       Win, W1, bin, b1, W2, CWp, cb, (s16x8*)w2f);
    hipLaunchKernelGGL(k_pab, dim3(16, 8, 2), dim3(256), 0, stream, x, CWp, pap, pbp);
    hipLaunchKernelGGL(k_out, dim3(4, 64, 4), dim3(256), 0, stream,
                       pap, pbp, cb, (const s16x8*)w2f, b2, (float*)d_out);
}

// Round 3
// 125.821 us; speedup vs baseline: 1.1577x; 1.0924x over previous
//
#include <hip/hip_runtime.h>

#define DIN 256
#define DHID 256
#define DEDGE 64
#define GS 68       // fp32 LDS tile row stride (dwords): 272 B, 16B-aligned, conflict-free

typedef float f32x4 __attribute__((ext_vector_type(4)));
typedef short s16x8 __attribute__((ext_vector_type(8)));
typedef unsigned int u32x4 __attribute__((ext_vector_type(4)));

// HW RNE pack: dst = {bf16(lo), bf16(hi)}
__device__ __forceinline__ unsigned int cvtpk(float lo, float hi) {
    unsigned int r;
    asm("v_cvt_pk_bf16_f32 %0, %1, %2" : "=v"(r) : "v"(lo), "v"(hi));
    return r;
}

// -------- Kernel 1: hp[kc][m][n] = sum_{k in 64-chunk kc} x[m][k] * Win[n][k]
// grid (16 mt, 4 nt, 5): z<4 = GEMM K-chunks (256 blocks); z==4 = W2->fragment-order
// bf16 precompute spread over the 64 (x,y) blocks, concurrent with the GEMM blocks.
__global__ __launch_bounds__(256) void k_xh(
    const float* __restrict__ x, const float* __restrict__ Win,
    float* __restrict__ hp, const float* __restrict__ W2, s16x8* __restrict__ W2f)
{
    const int tid = threadIdx.x;
    if (blockIdx.z == 4) {
        // fragment f = (k0*4+eb)*64 + quad*16 + l15  <-  W2[eb*16+l15][k0*32+quad*8 ..+8]
        if (tid < 32) {
            const int f = (((blockIdx.x << 2) + blockIdx.y) << 5) + tid;
            const int l15f = f & 15, qf = (f >> 4) & 3, ebf = (f >> 6) & 3, k0f = f >> 8;
            const int row = (ebf << 4) + l15f;
            const int col = (k0f << 5) + (qf << 3);
            const f32x4 w0 = *reinterpret_cast<const f32x4*>(&W2[row * DHID + col]);
            const f32x4 w1 = *reinterpret_cast<const f32x4*>(&W2[row * DHID + col + 4]);
            u32x4 wp;
            wp[0] = cvtpk(w0[0], w0[1]); wp[1] = cvtpk(w0[2], w0[3]);
            wp[2] = cvtpk(w1[0], w1[1]); wp[3] = cvtpk(w1[2], w1[3]);
            W2f[f] = __builtin_bit_cast(s16x8, wp);
        }
        return;
    }

    __shared__ float as[64 * GS];
    __shared__ float ws[64 * GS];
    const int m0 = blockIdx.x << 6, n0 = blockIdx.y << 6, k0 = blockIdx.z << 6;
    const int rr = tid >> 4;          // 0..15
    const int kk = (tid & 15) << 2;   // 0..60

#pragma unroll
    for (int it = 0; it < 4; ++it) {
        const int row = rr + (it << 4);
        *reinterpret_cast<f32x4*>(&as[row * GS + kk]) =
            *reinterpret_cast<const f32x4*>(&x[(m0 + row) * DIN + k0 + kk]);
        *reinterpret_cast<f32x4*>(&ws[row * GS + kk]) =
            *reinterpret_cast<const f32x4*>(&Win[(n0 + row) * DIN + k0 + kk]);
    }
    __syncthreads();

    const int tx = tid & 15, ty = tid >> 4;
    float acc[4][4] = {};
    for (int k = 0; k < 64; k += 4) {
        f32x4 av[4], wv[4];
#pragma unroll
        for (int r = 0; r < 4; ++r)
            av[r] = *reinterpret_cast<const f32x4*>(&as[(ty + (r << 4)) * GS + k]);
#pragma unroll
        for (int c = 0; c < 4; ++c)
            wv[c] = *reinterpret_cast<const f32x4*>(&ws[(tx + (c << 4)) * GS + k]);
#pragma unroll
        for (int r = 0; r < 4; ++r)
#pragma unroll
            for (int c = 0; c < 4; ++c)
                acc[r][c] += av[r][0]*wv[c][0] + av[r][1]*wv[c][1]
                           + av[r][2]*wv[c][2] + av[r][3]*wv[c][3];
    }
    float* dst = hp + ((size_t)blockIdx.z << 18);
#pragma unroll
    for (int r = 0; r < 4; ++r)
#pragma unroll
        for (int c = 0; c < 4; ++c)
            dst[(m0 + ty + (r << 4)) * DHID + n0 + tx + (c << 4)] = acc[r][c];
}

// -------- Kernel 2: pap/pbp[kc][m][g] = sum_{d in 128-chunk} h[m][d]*W1[g][half*256+d]
// h = hp0+hp1+hp2+hp3+b_in folded into A-staging. grid (16 mt, 8 = 4nt*2half, 2 kc) = 256.
__global__ __launch_bounds__(256) void k_pab(
    const float* __restrict__ hp, const float* __restrict__ W1,
    const float* __restrict__ bin, float* __restrict__ pap, float* __restrict__ pbp)
{
    __shared__ float as[64 * GS];
    __shared__ float ws[64 * GS];
    const int m0 = blockIdx.x << 6;
    const int half = blockIdx.y >> 2;
    const int n0 = (blockIdx.y & 3) << 6;
    const int kc = blockIdx.z;
    const int tid = threadIdx.x;
    const int rr = tid >> 4, kk = (tid & 15) << 2;
    const int tx = tid & 15, ty = tid >> 4;

    float acc[4][4] = {};
    for (int kt = 0; kt < 2; ++kt) {
        const int k0 = (kc << 7) + (kt << 6);
        if (kt) __syncthreads();
#pragma unroll
        for (int it = 0; it < 4; ++it) {
            const int row = rr + (it << 4);
            const int aoff = (m0 + row) * DHID + k0 + kk;
            f32x4 av = *reinterpret_cast<const f32x4*>(&hp[aoff]);
            av += *reinterpret_cast<const f32x4*>(&hp[aoff + (1 << 18)]);
            av += *reinterpret_cast<const f32x4*>(&hp[aoff + (2 << 18)]);
            av += *reinterpret_cast<const f32x4*>(&hp[aoff + (3 << 18)]);
            av += *reinterpret_cast<const f32x4*>(&bin[k0 + kk]);
            *reinterpret_cast<f32x4*>(&as[row * GS + kk]) = av;
            *reinterpret_cast<f32x4*>(&ws[row * GS + kk]) =
                *reinterpret_cast<const f32x4*>(&W1[(n0 + row) * 512 + (half << 8) + k0 + kk]);
        }
        __syncthreads();

        for (int k = 0; k < 64; k += 4) {
            f32x4 av[4], wv[4];
#pragma unroll
            for (int r = 0; r < 4; ++r)
                av[r] = *reinterpret_cast<const f32x4*>(&as[(ty + (r << 4)) * GS + k]);
#pragma unroll
            for (int c = 0; c < 4; ++c)
                wv[c] = *reinterpret_cast<const f32x4*>(&ws[(tx + (c << 4)) * GS + k]);
#pragma unroll
            for (int r = 0; r < 4; ++r)
#pragma unroll
                for (int c = 0; c < 4; ++c)
                    acc[r][c] += av[r][0]*wv[c][0] + av[r][1]*wv[c][1]
                               + av[r][2]*wv[c][2] + av[r][3]*wv[c][3];
        }
    }
    float* dst = (half ? pbp : pap) + ((size_t)kc << 18);
#pragma unroll
    for (int r = 0; r < 4; ++r)
#pragma unroll
        for (int c = 0; c < 4; ++c)
            dst[(m0 + ty + (r << 4)) * DHID + n0 + tx + (c << 4)] = acc[r][c];
}

// -------- Kernel 3: fused z=silu(pa_i+pb_j+b1); out = z@W2^T + b2 (MFMA) ----
// grid (4 jb, 64 i/4, 4 b), 256 thr = 4 waves; wave: 16 j x 64 e, 4 i at once.
// W2 arrives pre-converted in fragment order (W2f) -> staging is a linear s16x8
// copy: coalesced global reads AND conflict-free lane-linear LDS reads/writes.
__global__ __launch_bounds__(256) void k_out(
    const float* __restrict__ pap, const float* __restrict__ pbp,
    const float* __restrict__ b1, const s16x8* __restrict__ W2f,
    const float* __restrict__ b2, float* __restrict__ out)
{
    __shared__ s16x8 w2s[2048];      // 32 KB, fragment layout
    __shared__ float pab1[4][DHID];  // 4 KB

    const int jb = blockIdx.x, i0 = blockIdx.y << 2, b = blockIdx.z;
    const int tid = threadIdx.x;

    {
        const float b1v = b1[tid];
#pragma unroll
        for (int ii = 0; ii < 4; ++ii) {
            const int off = (((b << 8) + i0 + ii) << 8) + tid;
            pab1[ii][tid] = pap[off] + pap[off + (1 << 18)] + b1v;
        }
    }
#pragma unroll
    for (int it = 0; it < 8; ++it)
        w2s[tid + (it << 8)] = W2f[tid + (it << 8)];
    __syncthreads();

    const int lane = tid & 63, wave = tid >> 6, quad = lane >> 4, l15 = lane & 15;
    const int j0 = (jb << 6) + (wave << 4);
    const int pboff = (((b << 8) + (j0 + l15)) << 8);
    const float* pbq0 = pbp + pboff;
    const float* pbq1 = pbp + (1 << 18) + pboff;

    f32x4 acc[4][4];   // [ii][eb]
#pragma unroll
    for (int ii = 0; ii < 4; ++ii)
#pragma unroll
        for (int eb = 0; eb < 4; ++eb) acc[ii][eb] = (f32x4){0.f, 0.f, 0.f, 0.f};

    float b2v[4];
#pragma unroll
    for (int eb = 0; eb < 4; ++eb) b2v[eb] = b2[(eb << 4) + l15];

    for (int k0 = 0; k0 < 8; ++k0) {
        const int g = (k0 << 5) + (quad << 3);
        const f32x4 p0 = *reinterpret_cast<const f32x4*>(pbq0 + g)
                       + *reinterpret_cast<const f32x4*>(pbq1 + g);
        const f32x4 p1 = *reinterpret_cast<const f32x4*>(pbq0 + g + 4)
                       + *reinterpret_cast<const f32x4*>(pbq1 + g + 4);

        s16x8 bfrag[4];
#pragma unroll
        for (int eb = 0; eb < 4; ++eb)
            bfrag[eb] = w2s[((k0 << 2) + eb) * 64 + lane];

#pragma unroll
        for (int ii = 0; ii < 4; ++ii) {
            const f32x4 q0 = *reinterpret_cast<const f32x4*>(&pab1[ii][g]);
            const f32x4 q1 = *reinterpret_cast<const f32x4*>(&pab1[ii][g + 4]);
            float s[8];
#pragma unroll
            for (int jj = 0; jj < 4; ++jj) {
                const float z0 = q0[jj] + p0[jj];
                const float z1 = q1[jj] + p1[jj];
                const float e0 = __expf(-z0);
                const float e1 = __expf(-z1);
                s[jj]     = z0 * __builtin_amdgcn_rcpf(1.0f + e0);
                s[4 + jj] = z1 * __builtin_amdgcn_rcpf(1.0f + e1);
            }
            u32x4 ap;
            ap[0] = cvtpk(s[0], s[1]); ap[1] = cvtpk(s[2], s[3]);
            ap[2] = cvtpk(s[4], s[5]); ap[3] = cvtpk(s[6], s[7]);
            const s16x8 a = __builtin_bit_cast(s16x8, ap);
#pragma unroll
            for (int eb = 0; eb < 4; ++eb)
                acc[ii][eb] = __builtin_amdgcn_mfma_f32_16x16x32_bf16(a, bfrag[eb], acc[ii][eb], 0, 0, 0);
        }
    }

#pragma unroll
    for (int ii = 0; ii < 4; ++ii) {
        const int obase = (((((b << 8) + i0 + ii) << 8) + j0 + (quad << 2)) << 6) + l15;
#pragma unroll
        for (int eb = 0; eb < 4; ++eb) {
#pragma unroll
            for (int r = 0; r < 4; ++r)
                __builtin_nontemporal_store(acc[ii][eb][r] + b2v[eb],
                                            &out[obase + (r << 6) + (eb << 4)]);
        }
    }
}

extern "C" void kernel_launch(void* const* d_in, const int* in_sizes, int n_in,
                              void* d_out, int out_size, void* d_ws, size_t ws_size,
                              hipStream_t stream) {
    const float* x = 0; const float* Win = 0; const float* bin = 0;
    const float* W1 = 0; const float* b1 = 0; const float* W2 = 0; const float* b2 = 0;
    for (int idx = 0; idx < n_in; ++idx) {
        const int s = in_sizes[idx];
        if (s == 262144) x = (const float*)d_in[idx];
        else if (s == 131072) W1 = (const float*)d_in[idx];
        else if (s == 65536) Win = (const float*)d_in[idx];
        else if (s == 16384) W2 = (const float*)d_in[idx];
        else if (s == 64) b2 = (const float*)d_in[idx];
        else if (s == 256) { if (!bin) bin = (const float*)d_in[idx]; else b1 = (const float*)d_in[idx]; }
    }

    // ws layout (floats): hp 4x(1<<18) | pap 2x(1<<18) | pbp 2x(1<<18) | W2f 8192 (32 KB)
    float* ws  = (float*)d_ws;
    float* hp  = ws;
    float* pap = hp + (4 << 18);
    float* pbp = pap + (2 << 18);
    float* w2f = pbp + (2 << 18);

    hipLaunchKernelGGL(k_xh,  dim3(16, 4, 5), dim3(256), 0, stream, x, Win, hp, W2, (s16x8*)w2f);
    hipLaunchKernelGGL(k_pab, dim3(16, 8, 2), dim3(256), 0, stream, hp, W1, bin, pap, pbp);
    hipLaunchKernelGGL(k_out, dim3(4, 64, 4), dim3(256), 0, stream,
                       pap, pbp, b1, (const s16x8*)w2f, b2, (float*)d_out);
}